// Round 1
// baseline (434.684 us; speedup 1.0000x reference)
//
#include <hip/hip_runtime.h>

#define Bn 65536
#define Tn 100
#define Cn 7

typedef short short8 __attribute__((ext_vector_type(8)));   // 8 bf16 = 4 VGPRs (MFMA A/B frag)
typedef float float4v __attribute__((ext_vector_type(4)));  // MFMA C/D frag

__device__ __forceinline__ float fast_rcp(float x) { return __builtin_amdgcn_rcpf(x); }
__device__ __forceinline__ float sig_f(float x) { return fast_rcp(1.f + __expf(-x)); }
__device__ __forceinline__ float tanh_f(float x) { return 1.f - 2.f * fast_rcp(__expf(2.f * x) + 1.f); }
// round-to-nearest-even fp32 -> bf16 (finite values only)
__device__ __forceinline__ unsigned bf16rne(float x) {
    unsigned u = __float_as_uint(x);
    return (u + 0x7fffu + ((u >> 16) & 1u)) >> 16;
}
__device__ __forceinline__ float bf_lo(unsigned u) { return __uint_as_float(u << 16); }
__device__ __forceinline__ float bf_hi(unsigned u) { return __uint_as_float(u & 0xffff0000u); }

typedef const __attribute__((address_space(1))) void* gp_t;
typedef __attribute__((address_space(3))) void* sp_t;
__device__ __forceinline__ void async_copy_dw(const void* g, void* l) {
    __builtin_amdgcn_global_load_lds((gp_t)g, (sp_t)l, 4, 0, 0);
}

// ---------------- K0: gather fc1_w into per-(window,dir) bf16 B-panels ----------------
// w2g[10][2][64][32] bf16: kk=2*tt+i <-> fc1_w[n][4*t+2*d+i], t = d? 99-10w-tt : 10w+tt;
// kk in [20,32) zero (K pad to 32 for one 16x16x32 MFMA per tile).
__global__ void w2prep_kernel(const float* __restrict__ fc1_w, unsigned short* __restrict__ w2g) {
    int idx = blockIdx.x * 256 + threadIdx.x;   // 40960 total
    int w  = idx >> 12;
    int d  = (idx >> 11) & 1;
    int n  = (idx >> 5) & 63;
    int kk = idx & 31;
    int tt = kk >> 1, i = kk & 1;
    int t  = d ? (99 - 10 * w - tt) : (10 * w + tt);
    float v = (kk < 20) ? fc1_w[n * 400 + 4 * t + 2 * d + i] : 0.f;
    w2g[idx] = (unsigned short)bf16rne(v);
}

// ---------------- K1: bidirectional LSTM layer 0 ----------------
// h1 packed bf16 [T][2][B] uint (1 store/step); chunk barrier waits vmcnt(5) —
// drains the 35 staged loads but leaves the 5 fresh h1 stores in flight.
__global__ __launch_bounds__(256) void l0_kernel(
    const float* __restrict__ x,
    const float* __restrict__ wih_f, const float* __restrict__ whh_f,
    const float* __restrict__ bih_f, const float* __restrict__ bhh_f,
    const float* __restrict__ wih_r, const float* __restrict__ whh_r,
    const float* __restrict__ bih_r, const float* __restrict__ bhh_r,
    unsigned* __restrict__ h1u)
{
    __shared__ float xs[2][2][4480];   // [parity][dir][128 samples * 35 floats]

    const int tid  = threadIdx.x;
    const int rev  = tid >> 7;
    const int s    = tid & 127;
    const int b    = blockIdx.x * 128 + s;
    const int w    = tid >> 6;
    const int lane = tid & 63;
    const int sdir = w >> 1;
    const int half = w & 1;

    const float* wih = rev ? wih_r : wih_f;
    const float* whh = rev ? whh_r : whh_f;
    const float* bih = rev ? bih_r : bih_f;
    const float* bhh = rev ? bhh_r : bhh_f;

    float wi[56], wh[16], bias[8];
#pragma unroll
    for (int k = 0; k < 56; ++k) wi[k] = wih[k];
#pragma unroll
    for (int k = 0; k < 16; ++k) wh[k] = whh[k];
#pragma unroll
    for (int k = 0; k < 8; ++k) bias[k] = bih[k] + bhh[k];

    const int e  = (lane >= 35) ? 1 : 0;
    const int r0 = lane - 35 * e;
    const int s0 = half * 64 + e;
    const float* xsamp = x + (size_t)(blockIdx.x * 128 + s0) * 700;

    auto stage = [&](int ch, int p) {
        const int off = sdir ? (665 - 35 * ch) : (35 * ch);
        const float* g = xsamp + off + r0;
        float* l = &xs[p][sdir][half * 2240 + lane];
        int r = r0;
#pragma unroll
        for (int i = 0; i < 35; ++i) {
            async_copy_dw(g, l);
            l += 64;
            const int c = (r >= 6) ? 1 : 0;
            g += c ? 1394 : 729;
            r += c ? -6 : 29;
        }
    };

    float h0 = 0.f, h1v = 0.f, c0 = 0.f, c1 = 0.f;

    stage(0, 0);
#pragma unroll 1
    for (int ch = 0; ch < 20; ++ch) {
        // vmcnt(5): drain the 35 chunk loads, leave the 5 newest (h1 stores) in flight
        if (ch == 0) __builtin_amdgcn_s_waitcnt(0x0F70);
        else         __builtin_amdgcn_s_waitcnt(0x0F75);
        __syncthreads();
        if (ch < 19) stage(ch + 1, (ch + 1) & 1);
        __builtin_amdgcn_sched_barrier(0);   // keep stage loads older than compute's stores

        const int t0 = rev ? (95 - 5 * ch) : (5 * ch);
        const float* xbuf = &xs[ch & 1][rev][0];
#pragma unroll 1
        for (int tt = 0; tt < 5; ++tt) {
            const int rr = rev ? (4 - tt) : tt;
            const int t  = t0 + rr;
            const float* xrow = xbuf + s * 35 + rr * 7;

            float g[8];
#pragma unroll
            for (int k = 0; k < 8; ++k) g[k] = bias[k];
#pragma unroll
            for (int c = 0; c < 7; ++c) {
                const float xv = xrow[c];
#pragma unroll
                for (int k = 0; k < 8; ++k) g[k] = fmaf(wi[k * 7 + c], xv, g[k]);
            }
#pragma unroll
            for (int k = 0; k < 8; ++k)
                g[k] = fmaf(wh[k * 2], h0, fmaf(wh[k * 2 + 1], h1v, g[k]));

            const float i0 = sig_f(g[0]), i1 = sig_f(g[1]);
            const float f0 = sig_f(g[2]), f1 = sig_f(g[3]);
            const float q0 = tanh_f(g[4]), q1 = tanh_f(g[5]);
            const float o0 = sig_f(g[6]), o1 = sig_f(g[7]);
            c0 = fmaf(f0, c0, i0 * q0);
            c1 = fmaf(f1, c1, i1 * q1);
            h0  = o0 * tanh_f(c0);
            h1v = o1 * tanh_f(c1);

            h1u[((size_t)t * 2 + rev) * Bn + b] = bf16rne(h0) | (bf16rne(h1v) << 16);
        }
    }
}

// ---------------- K2: LSTM layer 1 + MFMA-fc1 + fc2 ----------------
// 10 windows x 10 steps. h1 slab (2 planes x 2 dirs x 10 t x 128 samples, packed bf16)
// double-buffered via async global_load_lds -> the step loop has ZERO global loads.
// a2 panel stride 20 dw (16B-aligned b128, <=2-way banks). MFMA K=32 per window per dir.
__global__ __launch_bounds__(256) void l1fc_kernel(
    const unsigned* __restrict__ hin,   // [T][2][B] packed bf16 pairs
    const float* __restrict__ wih_f, const float* __restrict__ whh_f,
    const float* __restrict__ bih_f, const float* __restrict__ bhh_f,
    const float* __restrict__ wih_r, const float* __restrict__ whh_r,
    const float* __restrict__ bih_r, const float* __restrict__ bhh_r,
    const unsigned* __restrict__ w2g,   // [10][2][64][32] bf16 = [10][2][64][16] dw
    const float* __restrict__ fc1_b,
    const float* __restrict__ fc2_w,    // [20][64]
    const float* __restrict__ fc2_b,
    float* __restrict__ out)            // [B][20]
{
    __shared__ unsigned smem[19456];    // 77,824 B -> 2 blocks/CU
    unsigned* a2  = smem;               // [2][128][20] dw (bf16 pairs; cols 10..15 zero K-pad)
    unsigned* w2b = smem + 5120;        // [2 buf][2 d][64][16] dw
    unsigned* hst = smem + 9216;        // [2 buf][2 d][2 p][10][128] dw

    const int tid  = threadIdx.x;
    const int ww   = tid >> 6;
    const int lane = tid & 63;
    const int d    = ww >> 1;
    const int half = ww & 1;
    const int sm   = half * 64 + lane;
    const int b0   = blockIdx.x * 128;

    const float* wih = d ? wih_r : wih_f;
    const float* whh = d ? whh_r : whh_f;
    const float* bih = d ? bih_r : bih_f;
    const float* bhh = d ? bhh_r : bhh_f;

    float wi[32], wh[16], bias[8];
#pragma unroll
    for (int k = 0; k < 32; ++k) wi[k] = wih[k];
#pragma unroll
    for (int k = 0; k < 16; ++k) wh[k] = whh[k];
#pragma unroll
    for (int k = 0; k < 8; ++k) bias[k] = bih[k] + bhh[k];

    float4v acc[2][4];
#pragma unroll
    for (int mt = 0; mt < 2; ++mt)
#pragma unroll
        for (int nt = 0; nt < 4; ++nt) acc[mt][nt] = (float4v){0.f, 0.f, 0.f, 0.f};

    for (int i = tid; i < 5120; i += 256) a2[i] = 0u;   // zero incl. K-pad cols

    // stage h slab for window w into buffer pb: rows R=[dd][p][j] of 128 dwords
    auto stage_h = [&](int w, int pb) {
        unsigned* dst = hst + pb * 5120;
        const int Rb = tid >> 7;           // 0/1
        const int s  = tid & 127;
#pragma unroll
        for (int i = 0; i < 20; ++i) {
            const int R  = Rb + 2 * i;     // 0..39
            const int dd = (R >= 20) ? 1 : 0;
            const int r2 = R - 20 * dd;
            const int p  = (r2 >= 10) ? 1 : 0;
            const int j  = r2 - 10 * p;
            const int t  = dd ? (99 - (10 * w + j)) : (10 * w + j);
            async_copy_dw(hin + ((size_t)t * 2 + p) * Bn + b0 + s, dst + R * 128 + s);
        }
    };
    auto stage_w = [&](int w, int pb) {
        const unsigned* src = w2g + w * 2048;
        unsigned* dst = w2b + pb * 2048;
#pragma unroll
        for (int i = 0; i < 8; ++i)
            async_copy_dw(src + i * 256 + tid, dst + i * 256 + tid);
    };

    stage_h(0, 0); stage_w(0, 0);

    float h0 = 0.f, h1v = 0.f, c0 = 0.f, c1 = 0.f;
    const int q = lane >> 4, l16 = lane & 15;

#pragma unroll 1
    for (int w = 0; w < 10; ++w) {
        __builtin_amdgcn_s_waitcnt(0x0F70);   // this window's slabs arrived
        __syncthreads();                      // (also covers a2-zero at w=0)
        if (w < 9) { stage_h(w + 1, (w + 1) & 1); stage_w(w + 1, (w + 1) & 1); }

        // ---- 10 LSTM steps (LDS-only inputs) ----
        const unsigned* hb = hst + (w & 1) * 5120 + d * 2560;
#pragma unroll 1
        for (int j = 0; j < 10; ++j) {
            const unsigned uF = hb[j * 128 + sm];
            const unsigned uR = hb[1280 + j * 128 + sm];
            const float aF0 = bf_lo(uF), aF1 = bf_hi(uF);
            const float aR0 = bf_lo(uR), aR1 = bf_hi(uR);

            float g[8];
#pragma unroll
            for (int k = 0; k < 8; ++k) {
                g[k] = bias[k];
                g[k] = fmaf(wi[k * 4 + 0], aF0, g[k]);
                g[k] = fmaf(wi[k * 4 + 1], aF1, g[k]);
                g[k] = fmaf(wi[k * 4 + 2], aR0, g[k]);
                g[k] = fmaf(wi[k * 4 + 3], aR1, g[k]);
                g[k] = fmaf(wh[k * 2], h0, fmaf(wh[k * 2 + 1], h1v, g[k]));
            }
            const float i0 = sig_f(g[0]), i1 = sig_f(g[1]);
            const float f0 = sig_f(g[2]), f1 = sig_f(g[3]);
            const float q0 = tanh_f(g[4]), q1 = tanh_f(g[5]);
            const float o0 = sig_f(g[6]), o1 = sig_f(g[7]);
            c0 = fmaf(f0, c0, i0 * q0);
            c1 = fmaf(f1, c1, i1 * q1);
            h0  = o0 * tanh_f(c0);
            h1v = o1 * tanh_f(c1);

            a2[d * 2560 + sm * 20 + j] = bf16rne(fmaxf(h0, 0.f)) | (bf16rne(fmaxf(h1v, 0.f)) << 16);
        }
        __syncthreads();   // a2 complete

        // ---- MFMA: C[128x64] += A2[dd]·W2[dd]^T, K=32, both dirs ----
        {
            const unsigned* wb = w2b + (w & 1) * 2048;
#pragma unroll
            for (int dd = 0; dd < 2; ++dd) {
                short8 av[2], bv[4];
#pragma unroll
                for (int mt = 0; mt < 2; ++mt)
                    av[mt] = *(const short8*)&a2[dd * 2560 + (ww * 32 + mt * 16 + l16) * 20 + q * 4];
#pragma unroll
                for (int nt = 0; nt < 4; ++nt)
                    bv[nt] = *(const short8*)&wb[dd * 1024 + (nt * 16 + l16) * 16 + q * 4];
#pragma unroll
                for (int mt = 0; mt < 2; ++mt)
#pragma unroll
                    for (int nt = 0; nt < 4; ++nt)
                        acc[mt][nt] = __builtin_amdgcn_mfma_f32_16x16x32_bf16(
                            av[mt], bv[nt], acc[mt][nt], 0, 0, 0);
            }
        }
        // next window's top barrier separates these MFMA reads from the next a2 writes
    }
    __syncthreads();

    // ---- epilogue: C -> LDS, +bias, relu, fc2, out ----
    {
        float* eb = (float*)smem;          // [128][65]
#pragma unroll
        for (int mt = 0; mt < 2; ++mt)
#pragma unroll
            for (int nt = 0; nt < 4; ++nt)
#pragma unroll
                for (int r = 0; r < 4; ++r) {
                    const int sl = ww * 32 + mt * 16 + q * 4 + r;
                    const int cl = nt * 16 + l16;
                    eb[sl * 65 + cl] = acc[mt][nt][r];
                }
    }
    __syncthreads();

    const float* eb = (const float*)smem;
    const int sm2 = tid & 127;
    const int og  = (tid >> 7) * 10;
    float z[64];
#pragma unroll
    for (int k = 0; k < 64; ++k) z[k] = fmaxf(eb[sm2 * 65 + k] + fc1_b[k], 0.f);
    float y[10];
#pragma unroll
    for (int o = 0; o < 10; ++o) {
        float r2 = fc2_b[og + o];
#pragma unroll
        for (int k = 0; k < 64; ++k) r2 = fmaf(fc2_w[(og + o) * 64 + k], z[k], r2);
        y[o] = r2;
    }
    __syncthreads();
    float* ebw = (float*)smem;
#pragma unroll
    for (int o = 0; o < 10; ++o) ebw[sm2 * 20 + og + o] = y[o];
    __syncthreads();
    for (int f = tid; f < 2560; f += 256)
        out[(size_t)blockIdx.x * 2560 + f] = ebw[f];
}

extern "C" void kernel_launch(void* const* d_in, const int* in_sizes, int n_in,
                              void* d_out, int out_size, void* d_ws, size_t ws_size,
                              hipStream_t stream) {
    const float* x = (const float*)d_in[0];
    const float* w_ih_l0  = (const float*)d_in[1];
    const float* w_hh_l0  = (const float*)d_in[2];
    const float* b_ih_l0  = (const float*)d_in[3];
    const float* b_hh_l0  = (const float*)d_in[4];
    const float* w_ih_l0r = (const float*)d_in[5];
    const float* w_hh_l0r = (const float*)d_in[6];
    const float* b_ih_l0r = (const float*)d_in[7];
    const float* b_hh_l0r = (const float*)d_in[8];
    const float* w_ih_l1  = (const float*)d_in[9];
    const float* w_hh_l1  = (const float*)d_in[10];
    const float* b_ih_l1  = (const float*)d_in[11];
    const float* b_hh_l1  = (const float*)d_in[12];
    const float* w_ih_l1r = (const float*)d_in[13];
    const float* w_hh_l1r = (const float*)d_in[14];
    const float* b_ih_l1r = (const float*)d_in[15];
    const float* b_hh_l1r = (const float*)d_in[16];
    const float* fc1_w = (const float*)d_in[17];
    const float* fc1_b = (const float*)d_in[18];
    const float* fc2_w = (const float*)d_in[19];
    const float* fc2_b = (const float*)d_in[20];

    unsigned* h1u = (unsigned*)d_ws;                                // [100][2][65536] u32 = 52,428,800 B
    unsigned short* w2g = (unsigned short*)((char*)d_ws + (size_t)Tn * 2 * Bn * 4);  // 81,920 B

    w2prep_kernel<<<160, 256, 0, stream>>>(fc1_w, w2g);
    l0_kernel<<<512, 256, 0, stream>>>(x,
        w_ih_l0, w_hh_l0, b_ih_l0, b_hh_l0,
        w_ih_l0r, w_hh_l0r, b_ih_l0r, b_hh_l0r, h1u);
    l1fc_kernel<<<512, 256, 0, stream>>>(h1u,
        w_ih_l1, w_hh_l1, b_ih_l1, b_hh_l1,
        w_ih_l1r, w_hh_l1r, b_ih_l1r, b_hh_l1r,
        (const unsigned*)w2g, fc1_b, fc2_w, fc2_b, (float*)d_out);
}

// Round 2
// 433.488 us; speedup vs baseline: 1.0028x; 1.0028x over previous
//
#include <hip/hip_runtime.h>

#define Bn 65536
#define Tn 100
#define Cn 7

typedef short short8 __attribute__((ext_vector_type(8)));   // 8 bf16 = 4 VGPRs (MFMA A/B frag)
typedef float float4v __attribute__((ext_vector_type(4)));  // MFMA C/D frag

__device__ __forceinline__ float fast_rcp(float x) { return __builtin_amdgcn_rcpf(x); }
__device__ __forceinline__ float sig_f(float x) { return fast_rcp(1.f + __expf(-x)); }
__device__ __forceinline__ float tanh_f(float x) { return 1.f - 2.f * fast_rcp(__expf(2.f * x) + 1.f); }
// round-to-nearest-even fp32 -> bf16 (finite values only)
__device__ __forceinline__ unsigned bf16rne(float x) {
    unsigned u = __float_as_uint(x);
    return (u + 0x7fffu + ((u >> 16) & 1u)) >> 16;
}
__device__ __forceinline__ float bf_lo(unsigned u) { return __uint_as_float(u << 16); }
__device__ __forceinline__ float bf_hi(unsigned u) { return __uint_as_float(u & 0xffff0000u); }

typedef const __attribute__((address_space(1))) void* gp_t;
typedef __attribute__((address_space(3))) void* sp_t;
__device__ __forceinline__ void async_copy_dw(const void* g, void* l) {
    __builtin_amdgcn_global_load_lds((gp_t)g, (sp_t)l, 4, 0, 0);
}

// ---------------- K0: gather fc1_w into per-(window,dir) bf16 B-panels ----------------
// w2g[10][2][64][32] bf16: kk=2*tt+i <-> fc1_w[n][4*t+2*d+i], t = d? 99-10w-tt : 10w+tt;
// kk in [20,32) zero (K pad to 32 for one 16x16x32 MFMA per tile).
__global__ void w2prep_kernel(const float* __restrict__ fc1_w, unsigned short* __restrict__ w2g) {
    int idx = blockIdx.x * 256 + threadIdx.x;   // 40960 total
    int w  = idx >> 12;
    int d  = (idx >> 11) & 1;
    int n  = (idx >> 5) & 63;
    int kk = idx & 31;
    int tt = kk >> 1, i = kk & 1;
    int t  = d ? (99 - 10 * w - tt) : (10 * w + tt);
    float v = (kk < 20) ? fc1_w[n * 400 + 4 * t + 2 * d + i] : 0.f;
    w2g[idx] = (unsigned short)bf16rne(v);
}

// ---------------- K1: bidirectional LSTM layer 0 ----------------
// h1 packed bf16 [T][2][B] uint (1 store/step); chunk barrier waits vmcnt(5) —
// drains the 35 staged loads but leaves the 5 fresh h1 stores in flight.
// R1: tt loop fully unrolled so step t+1's x-FMAs (h-independent) schedule under
// step t's sigmoid/tanh dependency tail (VALUBusy was 48% at 2 waves/SIMD).
__global__ __launch_bounds__(256) void l0_kernel(
    const float* __restrict__ x,
    const float* __restrict__ wih_f, const float* __restrict__ whh_f,
    const float* __restrict__ bih_f, const float* __restrict__ bhh_f,
    const float* __restrict__ wih_r, const float* __restrict__ whh_r,
    const float* __restrict__ bih_r, const float* __restrict__ bhh_r,
    unsigned* __restrict__ h1u)
{
    __shared__ float xs[2][2][4480];   // [parity][dir][128 samples * 35 floats]

    const int tid  = threadIdx.x;
    const int rev  = tid >> 7;
    const int s    = tid & 127;
    const int b    = blockIdx.x * 128 + s;
    const int w    = tid >> 6;
    const int lane = tid & 63;
    const int sdir = w >> 1;
    const int half = w & 1;

    const float* wih = rev ? wih_r : wih_f;
    const float* whh = rev ? whh_r : whh_f;
    const float* bih = rev ? bih_r : bih_f;
    const float* bhh = rev ? bhh_r : bhh_f;

    float wi[56], wh[16], bias[8];
#pragma unroll
    for (int k = 0; k < 56; ++k) wi[k] = wih[k];
#pragma unroll
    for (int k = 0; k < 16; ++k) wh[k] = whh[k];
#pragma unroll
    for (int k = 0; k < 8; ++k) bias[k] = bih[k] + bhh[k];

    const int e  = (lane >= 35) ? 1 : 0;
    const int r0 = lane - 35 * e;
    const int s0 = half * 64 + e;
    const float* xsamp = x + (size_t)(blockIdx.x * 128 + s0) * 700;

    auto stage = [&](int ch, int p) {
        const int off = sdir ? (665 - 35 * ch) : (35 * ch);
        const float* g = xsamp + off + r0;
        float* l = &xs[p][sdir][half * 2240 + lane];
        int r = r0;
#pragma unroll
        for (int i = 0; i < 35; ++i) {
            async_copy_dw(g, l);
            l += 64;
            const int c = (r >= 6) ? 1 : 0;
            g += c ? 1394 : 729;
            r += c ? -6 : 29;
        }
    };

    float h0 = 0.f, h1v = 0.f, c0 = 0.f, c1 = 0.f;

    stage(0, 0);
#pragma unroll 1
    for (int ch = 0; ch < 20; ++ch) {
        // vmcnt(5): drain the 35 chunk loads, leave the 5 newest (h1 stores) in flight
        if (ch == 0) __builtin_amdgcn_s_waitcnt(0x0F70);
        else         __builtin_amdgcn_s_waitcnt(0x0F75);
        __syncthreads();
        if (ch < 19) stage(ch + 1, (ch + 1) & 1);
        __builtin_amdgcn_sched_barrier(0);   // keep stage loads older than compute's stores

        const int t0 = rev ? (95 - 5 * ch) : (5 * ch);
        const float* xbuf = &xs[ch & 1][rev][0];
#pragma unroll
        for (int tt = 0; tt < 5; ++tt) {
            const int rr = rev ? (4 - tt) : tt;
            const int t  = t0 + rr;
            const float* xrow = xbuf + s * 35 + rr * 7;

            float g[8];
#pragma unroll
            for (int k = 0; k < 8; ++k) g[k] = bias[k];
#pragma unroll
            for (int c = 0; c < 7; ++c) {
                const float xv = xrow[c];
#pragma unroll
                for (int k = 0; k < 8; ++k) g[k] = fmaf(wi[k * 7 + c], xv, g[k]);
            }
#pragma unroll
            for (int k = 0; k < 8; ++k)
                g[k] = fmaf(wh[k * 2], h0, fmaf(wh[k * 2 + 1], h1v, g[k]));

            const float i0 = sig_f(g[0]), i1 = sig_f(g[1]);
            const float f0 = sig_f(g[2]), f1 = sig_f(g[3]);
            const float q0 = tanh_f(g[4]), q1 = tanh_f(g[5]);
            const float o0 = sig_f(g[6]), o1 = sig_f(g[7]);
            c0 = fmaf(f0, c0, i0 * q0);
            c1 = fmaf(f1, c1, i1 * q1);
            h0  = o0 * tanh_f(c0);
            h1v = o1 * tanh_f(c1);

            h1u[((size_t)t * 2 + rev) * Bn + b] = bf16rne(h0) | (bf16rne(h1v) << 16);
        }
    }
}

// ---------------- K2: LSTM layer 1 + MFMA-fc1 + fc2 ----------------
// 10 windows x 10 steps. h1 slab (2 planes x 2 dirs x 10 t x 128 samples, packed bf16)
// double-buffered via async global_load_lds -> the step loop has ZERO global loads.
// a2 panel stride 20 dw (16B-aligned b128, <=2-way banks). MFMA K=32 per window per dir.
// R1: j loop unrolled x2 so step j+1's x-part overlaps step j's trans tail.
__global__ __launch_bounds__(256) void l1fc_kernel(
    const unsigned* __restrict__ hin,   // [T][2][B] packed bf16 pairs
    const float* __restrict__ wih_f, const float* __restrict__ whh_f,
    const float* __restrict__ bih_f, const float* __restrict__ bhh_f,
    const float* __restrict__ wih_r, const float* __restrict__ whh_r,
    const float* __restrict__ bih_r, const float* __restrict__ bhh_r,
    const unsigned* __restrict__ w2g,   // [10][2][64][32] bf16 = [10][2][64][16] dw
    const float* __restrict__ fc1_b,
    const float* __restrict__ fc2_w,    // [20][64]
    const float* __restrict__ fc2_b,
    float* __restrict__ out)            // [B][20]
{
    __shared__ unsigned smem[19456];    // 77,824 B -> 2 blocks/CU
    unsigned* a2  = smem;               // [2][128][20] dw (bf16 pairs; cols 10..15 zero K-pad)
    unsigned* w2b = smem + 5120;        // [2 buf][2 d][64][16] dw
    unsigned* hst = smem + 9216;        // [2 buf][2 d][2 p][10][128] dw

    const int tid  = threadIdx.x;
    const int ww   = tid >> 6;
    const int lane = tid & 63;
    const int d    = ww >> 1;
    const int half = ww & 1;
    const int sm   = half * 64 + lane;
    const int b0   = blockIdx.x * 128;

    const float* wih = d ? wih_r : wih_f;
    const float* whh = d ? whh_r : whh_f;
    const float* bih = d ? bih_r : bih_f;
    const float* bhh = d ? bhh_r : bhh_f;

    float wi[32], wh[16], bias[8];
#pragma unroll
    for (int k = 0; k < 32; ++k) wi[k] = wih[k];
#pragma unroll
    for (int k = 0; k < 16; ++k) wh[k] = whh[k];
#pragma unroll
    for (int k = 0; k < 8; ++k) bias[k] = bih[k] + bhh[k];

    float4v acc[2][4];
#pragma unroll
    for (int mt = 0; mt < 2; ++mt)
#pragma unroll
        for (int nt = 0; nt < 4; ++nt) acc[mt][nt] = (float4v){0.f, 0.f, 0.f, 0.f};

    for (int i = tid; i < 5120; i += 256) a2[i] = 0u;   // zero incl. K-pad cols

    // stage h slab for window w into buffer pb: rows R=[dd][p][j] of 128 dwords
    auto stage_h = [&](int w, int pb) {
        unsigned* dst = hst + pb * 5120;
        const int Rb = tid >> 7;           // 0/1
        const int s  = tid & 127;
#pragma unroll
        for (int i = 0; i < 20; ++i) {
            const int R  = Rb + 2 * i;     // 0..39
            const int dd = (R >= 20) ? 1 : 0;
            const int r2 = R - 20 * dd;
            const int p  = (r2 >= 10) ? 1 : 0;
            const int j  = r2 - 10 * p;
            const int t  = dd ? (99 - (10 * w + j)) : (10 * w + j);
            async_copy_dw(hin + ((size_t)t * 2 + p) * Bn + b0 + s, dst + R * 128 + s);
        }
    };
    auto stage_w = [&](int w, int pb) {
        const unsigned* src = w2g + w * 2048;
        unsigned* dst = w2b + pb * 2048;
#pragma unroll
        for (int i = 0; i < 8; ++i)
            async_copy_dw(src + i * 256 + tid, dst + i * 256 + tid);
    };

    stage_h(0, 0); stage_w(0, 0);

    float h0 = 0.f, h1v = 0.f, c0 = 0.f, c1 = 0.f;
    const int q = lane >> 4, l16 = lane & 15;

#pragma unroll 1
    for (int w = 0; w < 10; ++w) {
        __builtin_amdgcn_s_waitcnt(0x0F70);   // this window's slabs arrived
        __syncthreads();                      // (also covers a2-zero at w=0)
        if (w < 9) { stage_h(w + 1, (w + 1) & 1); stage_w(w + 1, (w + 1) & 1); }

        // ---- 10 LSTM steps (LDS-only inputs) ----
        const unsigned* hb = hst + (w & 1) * 5120 + d * 2560;
#pragma unroll 2
        for (int j = 0; j < 10; ++j) {
            const unsigned uF = hb[j * 128 + sm];
            const unsigned uR = hb[1280 + j * 128 + sm];
            const float aF0 = bf_lo(uF), aF1 = bf_hi(uF);
            const float aR0 = bf_lo(uR), aR1 = bf_hi(uR);

            float g[8];
#pragma unroll
            for (int k = 0; k < 8; ++k) {
                g[k] = bias[k];
                g[k] = fmaf(wi[k * 4 + 0], aF0, g[k]);
                g[k] = fmaf(wi[k * 4 + 1], aF1, g[k]);
                g[k] = fmaf(wi[k * 4 + 2], aR0, g[k]);
                g[k] = fmaf(wi[k * 4 + 3], aR1, g[k]);
                g[k] = fmaf(wh[k * 2], h0, fmaf(wh[k * 2 + 1], h1v, g[k]));
            }
            const float i0 = sig_f(g[0]), i1 = sig_f(g[1]);
            const float f0 = sig_f(g[2]), f1 = sig_f(g[3]);
            const float q0 = tanh_f(g[4]), q1 = tanh_f(g[5]);
            const float o0 = sig_f(g[6]), o1 = sig_f(g[7]);
            c0 = fmaf(f0, c0, i0 * q0);
            c1 = fmaf(f1, c1, i1 * q1);
            h0  = o0 * tanh_f(c0);
            h1v = o1 * tanh_f(c1);

            a2[d * 2560 + sm * 20 + j] = bf16rne(fmaxf(h0, 0.f)) | (bf16rne(fmaxf(h1v, 0.f)) << 16);
        }
        __syncthreads();   // a2 complete

        // ---- MFMA: C[128x64] += A2[dd]·W2[dd]^T, K=32, both dirs ----
        {
            const unsigned* wb = w2b + (w & 1) * 2048;
#pragma unroll
            for (int dd = 0; dd < 2; ++dd) {
                short8 av[2], bv[4];
#pragma unroll
                for (int mt = 0; mt < 2; ++mt)
                    av[mt] = *(const short8*)&a2[dd * 2560 + (ww * 32 + mt * 16 + l16) * 20 + q * 4];
#pragma unroll
                for (int nt = 0; nt < 4; ++nt)
                    bv[nt] = *(const short8*)&wb[dd * 1024 + (nt * 16 + l16) * 16 + q * 4];
#pragma unroll
                for (int mt = 0; mt < 2; ++mt)
#pragma unroll
                    for (int nt = 0; nt < 4; ++nt)
                        acc[mt][nt] = __builtin_amdgcn_mfma_f32_16x16x32_bf16(
                            av[mt], bv[nt], acc[mt][nt], 0, 0, 0);
            }
        }
        // next window's top barrier separates these MFMA reads from the next a2 writes
    }
    __syncthreads();

    // ---- epilogue: C -> LDS, +bias, relu, fc2, out ----
    {
        float* eb = (float*)smem;          // [128][65]
#pragma unroll
        for (int mt = 0; mt < 2; ++mt)
#pragma unroll
            for (int nt = 0; nt < 4; ++nt)
#pragma unroll
                for (int r = 0; r < 4; ++r) {
                    const int sl = ww * 32 + mt * 16 + q * 4 + r;
                    const int cl = nt * 16 + l16;
                    eb[sl * 65 + cl] = acc[mt][nt][r];
                }
    }
    __syncthreads();

    const float* eb = (const float*)smem;
    const int sm2 = tid & 127;
    const int og  = (tid >> 7) * 10;
    float z[64];
#pragma unroll
    for (int k = 0; k < 64; ++k) z[k] = fmaxf(eb[sm2 * 65 + k] + fc1_b[k], 0.f);
    float y[10];
#pragma unroll
    for (int o = 0; o < 10; ++o) {
        float r2 = fc2_b[og + o];
#pragma unroll
        for (int k = 0; k < 64; ++k) r2 = fmaf(fc2_w[(og + o) * 64 + k], z[k], r2);
        y[o] = r2;
    }
    __syncthreads();
    float* ebw = (float*)smem;
#pragma unroll
    for (int o = 0; o < 10; ++o) ebw[sm2 * 20 + og + o] = y[o];
    __syncthreads();
    for (int f = tid; f < 2560; f += 256)
        out[(size_t)blockIdx.x * 2560 + f] = ebw[f];
}

extern "C" void kernel_launch(void* const* d_in, const int* in_sizes, int n_in,
                              void* d_out, int out_size, void* d_ws, size_t ws_size,
                              hipStream_t stream) {
    const float* x = (const float*)d_in[0];
    const float* w_ih_l0  = (const float*)d_in[1];
    const float* w_hh_l0  = (const float*)d_in[2];
    const float* b_ih_l0  = (const float*)d_in[3];
    const float* b_hh_l0  = (const float*)d_in[4];
    const float* w_ih_l0r = (const float*)d_in[5];
    const float* w_hh_l0r = (const float*)d_in[6];
    const float* b_ih_l0r = (const float*)d_in[7];
    const float* b_hh_l0r = (const float*)d_in[8];
    const float* w_ih_l1  = (const float*)d_in[9];
    const float* w_hh_l1  = (const float*)d_in[10];
    const float* b_ih_l1  = (const float*)d_in[11];
    const float* b_hh_l1  = (const float*)d_in[12];
    const float* w_ih_l1r = (const float*)d_in[13];
    const float* w_hh_l1r = (const float*)d_in[14];
    const float* b_ih_l1r = (const float*)d_in[15];
    const float* b_hh_l1r = (const float*)d_in[16];
    const float* fc1_w = (const float*)d_in[17];
    const float* fc1_b = (const float*)d_in[18];
    const float* fc2_w = (const float*)d_in[19];
    const float* fc2_b = (const float*)d_in[20];

    unsigned* h1u = (unsigned*)d_ws;                                // [100][2][65536] u32 = 52,428,800 B
    unsigned short* w2g = (unsigned short*)((char*)d_ws + (size_t)Tn * 2 * Bn * 4);  // 81,920 B

    w2prep_kernel<<<160, 256, 0, stream>>>(fc1_w, w2g);
    l0_kernel<<<512, 256, 0, stream>>>(x,
        w_ih_l0, w_hh_l0, b_ih_l0, b_hh_l0,
        w_ih_l0r, w_hh_l0r, b_ih_l0r, b_hh_l0r, h1u);
    l1fc_kernel<<<512, 256, 0, stream>>>(h1u,
        w_ih_l1, w_hh_l1, b_ih_l1, b_hh_l1,
        w_ih_l1r, w_hh_l1r, b_ih_l1r, b_hh_l1r,
        (const unsigned*)w2g, fc1_b, fc2_w, fc2_b, (float*)d_out);
}

// Round 3
// 430.611 us; speedup vs baseline: 1.0095x; 1.0067x over previous
//
#include <hip/hip_runtime.h>

#define Bn 65536
#define Tn 100
#define Cn 7

typedef short short8 __attribute__((ext_vector_type(8)));   // 8 bf16 = 4 VGPRs (MFMA A/B frag)
typedef float float4v __attribute__((ext_vector_type(4)));  // MFMA C/D frag

__device__ __forceinline__ float fast_rcp(float x) { return __builtin_amdgcn_rcpf(x); }
__device__ __forceinline__ float sig_f(float x) { return fast_rcp(1.f + __expf(-x)); }
__device__ __forceinline__ float tanh_f(float x) { return 1.f - 2.f * fast_rcp(__expf(2.f * x) + 1.f); }
// round-to-nearest-even fp32 -> bf16 (finite values only)
__device__ __forceinline__ unsigned bf16rne(float x) {
    unsigned u = __float_as_uint(x);
    return (u + 0x7fffu + ((u >> 16) & 1u)) >> 16;
}
__device__ __forceinline__ float bf_lo(unsigned u) { return __uint_as_float(u << 16); }
__device__ __forceinline__ float bf_hi(unsigned u) { return __uint_as_float(u & 0xffff0000u); }

// lane^1 exchange via DPP quad_perm [1,0,3,2] — stays in the VALU pipe (no LDS)
__device__ __forceinline__ float dpp_xor1(float x) {
    return __uint_as_float((unsigned)__builtin_amdgcn_mov_dpp(
        (int)__float_as_uint(x), 0xB1, 0xF, 0xF, true));
}

typedef const __attribute__((address_space(1))) void* gp_t;
typedef __attribute__((address_space(3))) void* sp_t;
__device__ __forceinline__ void async_copy_dw(const void* g, void* l) {
    __builtin_amdgcn_global_load_lds((gp_t)g, (sp_t)l, 4, 0, 0);
}

// ---------------- K0: gather fc1_w into per-(window,dir) bf16 B-panels ----------------
__global__ void w2prep_kernel(const float* __restrict__ fc1_w, unsigned short* __restrict__ w2g) {
    int idx = blockIdx.x * 256 + threadIdx.x;   // 40960 total
    int w  = idx >> 12;
    int d  = (idx >> 11) & 1;
    int n  = (idx >> 5) & 63;
    int kk = idx & 31;
    int tt = kk >> 1, i = kk & 1;
    int t  = d ? (99 - 10 * w - tt) : (10 * w + tt);
    float v = (kk < 20) ? fc1_w[n * 400 + 4 * t + 2 * d + i] : 0.f;
    w2g[idx] = (unsigned short)bf16rne(v);
}

// ---------------- K1: bidirectional LSTM layer 0, channel-split ----------------
// R2: 2 threads per (sample,dir), one per hidden channel -> 512 thr/block, 4 waves/SIMD
// (was 2). Each thread: 4 gates, 10 trans/step. Partner h via DPP lane^1 swap.
// Staging identical to before (waves 0-3); vmcnt(5) discipline unchanged.
__global__ __launch_bounds__(512) void l0_kernel(
    const float* __restrict__ x,
    const float* __restrict__ wih_f, const float* __restrict__ whh_f,
    const float* __restrict__ bih_f, const float* __restrict__ bhh_f,
    const float* __restrict__ wih_r, const float* __restrict__ whh_r,
    const float* __restrict__ bih_r, const float* __restrict__ bhh_r,
    unsigned* __restrict__ h1u)
{
    __shared__ float xs[2][2][4480];   // [parity][dir][128 samples * 35 floats]

    const int tid  = threadIdx.x;
    const int wv   = tid >> 6;          // 0..7
    const int lane = tid & 63;
    const int rev  = tid >> 8;          // waves 0-3: fwd, 4-7: rev
    const int cid  = tid & 1;           // hidden channel
    const int s    = (tid & 255) >> 1;  // sample in block (0..127)
    const int b    = blockIdx.x * 128 + s;

    const float* wih = rev ? wih_r : wih_f;
    const float* whh = rev ? whh_r : whh_f;
    const float* bih = rev ? bih_r : bih_f;
    const float* bhh = rev ? bhh_r : bhh_f;

    // per-channel gate rows: k = cid + 2*j, j in {i,f,g,o}
    float wi[28], whA[4], whB[4], bias4[4];
#pragma unroll
    for (int j = 0; j < 4; ++j) {
        const int k = cid + 2 * j;
#pragma unroll
        for (int c = 0; c < 7; ++c) wi[j * 7 + c] = wih[k * 7 + c];
        whA[j] = whh[k * 2 + cid];        // coeff of own h
        whB[j] = whh[k * 2 + (cid ^ 1)];  // coeff of partner h
        bias4[j] = bih[k] + bhh[k];
    }

    // staging (waves 0-3 only): identical pattern to previous rounds
    const int sdir  = (wv >> 1) & 1;
    const int shalf = wv & 1;
    const int e  = (lane >= 35) ? 1 : 0;
    const int r0 = lane - 35 * e;
    const int s0 = shalf * 64 + e;
    const float* xsamp = x + (size_t)(blockIdx.x * 128 + s0) * 700;

    auto stage = [&](int ch, int p) {
        const int off = sdir ? (665 - 35 * ch) : (35 * ch);
        const float* g = xsamp + off + r0;
        float* l = &xs[p][sdir][shalf * 2240 + lane];
        int r = r0;
#pragma unroll
        for (int i = 0; i < 35; ++i) {
            async_copy_dw(g, l);
            l += 64;
            const int c = (r >= 6) ? 1 : 0;
            g += c ? 1394 : 729;
            r += c ? -6 : 29;
        }
    };

    float hs = 0.f, ho = 0.f, cc = 0.f;

    if (wv < 4) stage(0, 0);
#pragma unroll 1
    for (int chk = 0; chk < 20; ++chk) {
        // waves 0-3: drain 35 chunk loads, leave 5 h1 stores in flight.
        // waves 4-7: only 5 stores outstanding -> no-op wait; barrier covers them.
        if (chk == 0) __builtin_amdgcn_s_waitcnt(0x0F70);
        else          __builtin_amdgcn_s_waitcnt(0x0F75);
        __syncthreads();
        if (wv < 4 && chk < 19) stage(chk + 1, (chk + 1) & 1);
        __builtin_amdgcn_sched_barrier(0);   // keep stage loads older than compute's stores

        const int t0 = rev ? (95 - 5 * chk) : (5 * chk);
        const float* xbuf = &xs[chk & 1][rev][0];
#pragma unroll
        for (int tt = 0; tt < 5; ++tt) {
            const int rr = rev ? (4 - tt) : tt;
            const int t  = t0 + rr;
            const float* xrow = xbuf + s * 35 + rr * 7;

            float g[4];
#pragma unroll
            for (int j = 0; j < 4; ++j) g[j] = bias4[j];
#pragma unroll
            for (int c = 0; c < 7; ++c) {
                const float xv = xrow[c];
#pragma unroll
                for (int j = 0; j < 4; ++j) g[j] = fmaf(wi[j * 7 + c], xv, g[j]);
            }
#pragma unroll
            for (int j = 0; j < 4; ++j)
                g[j] = fmaf(whA[j], hs, fmaf(whB[j], ho, g[j]));

            const float iv = sig_f(g[0]);
            const float fv = sig_f(g[1]);
            const float qv = tanh_f(g[2]);
            const float ov = sig_f(g[3]);
            cc = fmaf(fv, cc, iv * qv);
            hs = ov * tanh_f(cc);
            ho = dpp_xor1(hs);          // partner channel's h

            if (cid == 0)               // even lanes: pack (h0,h1), 1 store/step/wave
                h1u[((size_t)t * 2 + rev) * Bn + b] = bf16rne(hs) | (bf16rne(ho) << 16);
        }
    }
}

// ---------------- K2: LSTM layer 1 + MFMA-fc1 + fc2, channel-split ----------------
// R2: 512 threads (2 per (sample,dir)); MFMA re-partitioned to 8 waves x 16 rows.
__global__ __launch_bounds__(512) void l1fc_kernel(
    const unsigned* __restrict__ hin,   // [T][2][B] packed bf16 pairs
    const float* __restrict__ wih_f, const float* __restrict__ whh_f,
    const float* __restrict__ bih_f, const float* __restrict__ bhh_f,
    const float* __restrict__ wih_r, const float* __restrict__ whh_r,
    const float* __restrict__ bih_r, const float* __restrict__ bhh_r,
    const unsigned* __restrict__ w2g,   // [10][2][64][32] bf16 = [10][2][64][16] dw
    const float* __restrict__ fc1_b,
    const float* __restrict__ fc2_w,    // [20][64]
    const float* __restrict__ fc2_b,
    float* __restrict__ out)            // [B][20]
{
    __shared__ unsigned smem[19456];    // 77,824 B -> 2 blocks/CU
    unsigned* a2  = smem;               // [2][128][20] dw (bf16 pairs; cols 10..15 zero K-pad)
    unsigned* w2b = smem + 5120;        // [2 buf][2 d][64][16] dw
    unsigned* hst = smem + 9216;        // [2 buf][2 d][2 p][10][128] dw

    const int tid  = threadIdx.x;
    const int wv   = tid >> 6;          // 0..7
    const int lane = tid & 63;
    const int d    = tid >> 8;          // waves 0-3: fwd, 4-7: rev
    const int cid  = tid & 1;
    const int s    = (tid & 255) >> 1;  // 0..127
    const int b0   = blockIdx.x * 128;

    const float* wih = d ? wih_r : wih_f;
    const float* whh = d ? whh_r : whh_f;
    const float* bih = d ? bih_r : bih_f;
    const float* bhh = d ? bhh_r : bhh_f;

    float wi[16], whA[4], whB[4], bias4[4];
#pragma unroll
    for (int j = 0; j < 4; ++j) {
        const int k = cid + 2 * j;
#pragma unroll
        for (int m = 0; m < 4; ++m) wi[j * 4 + m] = wih[k * 4 + m];
        whA[j] = whh[k * 2 + cid];
        whB[j] = whh[k * 2 + (cid ^ 1)];
        bias4[j] = bih[k] + bhh[k];
    }

    float4v acc[4];
#pragma unroll
    for (int nt = 0; nt < 4; ++nt) acc[nt] = (float4v){0.f, 0.f, 0.f, 0.f};

    for (int i = tid; i < 5120; i += 512) a2[i] = 0u;   // zero incl. K-pad cols

    // stage h slab for window w into buffer pb: rows R=[dd][p][j] of 128 dwords
    auto stage_h = [&](int w, int pb) {
        unsigned* dst = hst + pb * 5120;
        const int Rb = tid >> 7;           // 0..3
        const int s2 = tid & 127;
#pragma unroll
        for (int i = 0; i < 10; ++i) {
            const int R  = Rb + 4 * i;     // 0..39
            const int dd = (R >= 20) ? 1 : 0;
            const int r2 = R - 20 * dd;
            const int p  = (r2 >= 10) ? 1 : 0;
            const int j  = r2 - 10 * p;
            const int t  = dd ? (99 - (10 * w + j)) : (10 * w + j);
            async_copy_dw(hin + ((size_t)t * 2 + p) * Bn + b0 + s2, dst + R * 128 + s2);
        }
    };
    auto stage_w = [&](int w, int pb) {
        const unsigned* src = w2g + w * 2048;
        unsigned* dst = w2b + pb * 2048;
#pragma unroll
        for (int i = 0; i < 4; ++i)
            async_copy_dw(src + i * 512 + tid, dst + i * 512 + tid);
    };

    stage_h(0, 0); stage_w(0, 0);

    float hs = 0.f, ho = 0.f, cc = 0.f;
    const int q = lane >> 4, l16 = lane & 15;

#pragma unroll 1
    for (int w = 0; w < 10; ++w) {
        __builtin_amdgcn_s_waitcnt(0x0F70);   // this window's slabs arrived
        __syncthreads();                      // (also covers a2-zero at w=0)
        if (w < 9) { stage_h(w + 1, (w + 1) & 1); stage_w(w + 1, (w + 1) & 1); }

        // ---- 10 LSTM steps (LDS-only inputs) ----
        const unsigned* hb = hst + (w & 1) * 5120 + d * 2560;
#pragma unroll 2
        for (int j = 0; j < 10; ++j) {
            const unsigned uF = hb[j * 128 + s];
            const unsigned uR = hb[1280 + j * 128 + s];
            const float aF0 = bf_lo(uF), aF1 = bf_hi(uF);
            const float aR0 = bf_lo(uR), aR1 = bf_hi(uR);

            float g[4];
#pragma unroll
            for (int jj = 0; jj < 4; ++jj) {
                g[jj] = bias4[jj];
                g[jj] = fmaf(wi[jj * 4 + 0], aF0, g[jj]);
                g[jj] = fmaf(wi[jj * 4 + 1], aF1, g[jj]);
                g[jj] = fmaf(wi[jj * 4 + 2], aR0, g[jj]);
                g[jj] = fmaf(wi[jj * 4 + 3], aR1, g[jj]);
                g[jj] = fmaf(whA[jj], hs, fmaf(whB[jj], ho, g[jj]));
            }
            const float iv = sig_f(g[0]);
            const float fv = sig_f(g[1]);
            const float qv = tanh_f(g[2]);
            const float ov = sig_f(g[3]);
            cc = fmaf(fv, cc, iv * qv);
            hs = ov * tanh_f(cc);
            ho = dpp_xor1(hs);

            if (cid == 0)
                a2[d * 2560 + s * 20 + j] =
                    bf16rne(fmaxf(hs, 0.f)) | (bf16rne(fmaxf(ho, 0.f)) << 16);
        }
        __syncthreads();   // a2 complete

        // ---- MFMA: C[128x64] += A2[dd]·W2[dd]^T, K=32; 8 waves x 16 rows ----
        {
            const unsigned* wb = w2b + (w & 1) * 2048;
#pragma unroll
            for (int dd = 0; dd < 2; ++dd) {
                short8 av = *(const short8*)&a2[dd * 2560 + (wv * 16 + l16) * 20 + q * 4];
                short8 bv[4];
#pragma unroll
                for (int nt = 0; nt < 4; ++nt)
                    bv[nt] = *(const short8*)&wb[dd * 1024 + (nt * 16 + l16) * 16 + q * 4];
#pragma unroll
                for (int nt = 0; nt < 4; ++nt)
                    acc[nt] = __builtin_amdgcn_mfma_f32_16x16x32_bf16(
                        av, bv[nt], acc[nt], 0, 0, 0);
            }
        }
        // next window's top barrier separates these MFMA reads from the next a2 writes
    }
    __syncthreads();

    // ---- epilogue: C -> LDS, +bias, relu, fc2, out ----
    {
        float* eb = (float*)smem;          // [128][65]
#pragma unroll
        for (int nt = 0; nt < 4; ++nt)
#pragma unroll
            for (int r = 0; r < 4; ++r) {
                const int sl = wv * 16 + q * 4 + r;
                const int cl = nt * 16 + l16;
                eb[sl * 65 + cl] = acc[nt][r];
            }
    }
    __syncthreads();

    const float* eb = (const float*)smem;
    const int sm2 = tid & 127;
    const int og  = (tid >> 7) * 5;        // 4 groups x 5 outputs
    float z[64];
#pragma unroll
    for (int k = 0; k < 64; ++k) z[k] = fmaxf(eb[sm2 * 65 + k] + fc1_b[k], 0.f);
    float y[5];
#pragma unroll
    for (int o = 0; o < 5; ++o) {
        float r2 = fc2_b[og + o];
#pragma unroll
        for (int k = 0; k < 64; ++k) r2 = fmaf(fc2_w[(og + o) * 64 + k], z[k], r2);
        y[o] = r2;
    }
    __syncthreads();
    float* ebw = (float*)smem;
#pragma unroll
    for (int o = 0; o < 5; ++o) ebw[sm2 * 20 + og + o] = y[o];
    __syncthreads();
    for (int f = tid; f < 2560; f += 512)
        out[(size_t)blockIdx.x * 2560 + f] = ebw[f];
}

extern "C" void kernel_launch(void* const* d_in, const int* in_sizes, int n_in,
                              void* d_out, int out_size, void* d_ws, size_t ws_size,
                              hipStream_t stream) {
    const float* x = (const float*)d_in[0];
    const float* w_ih_l0  = (const float*)d_in[1];
    const float* w_hh_l0  = (const float*)d_in[2];
    const float* b_ih_l0  = (const float*)d_in[3];
    const float* b_hh_l0  = (const float*)d_in[4];
    const float* w_ih_l0r = (const float*)d_in[5];
    const float* w_hh_l0r = (const float*)d_in[6];
    const float* b_ih_l0r = (const float*)d_in[7];
    const float* b_hh_l0r = (const float*)d_in[8];
    const float* w_ih_l1  = (const float*)d_in[9];
    const float* w_hh_l1  = (const float*)d_in[10];
    const float* b_ih_l1  = (const float*)d_in[11];
    const float* b_hh_l1  = (const float*)d_in[12];
    const float* w_ih_l1r = (const float*)d_in[13];
    const float* w_hh_l1r = (const float*)d_in[14];
    const float* b_ih_l1r = (const float*)d_in[15];
    const float* b_hh_l1r = (const float*)d_in[16];
    const float* fc1_w = (const float*)d_in[17];
    const float* fc1_b = (const float*)d_in[18];
    const float* fc2_w = (const float*)d_in[19];
    const float* fc2_b = (const float*)d_in[20];

    unsigned* h1u = (unsigned*)d_ws;                                // [100][2][65536] u32 = 52,428,800 B
    unsigned short* w2g = (unsigned short*)((char*)d_ws + (size_t)Tn * 2 * Bn * 4);  // 81,920 B

    w2prep_kernel<<<160, 256, 0, stream>>>(fc1_w, w2g);
    l0_kernel<<<512, 512, 0, stream>>>(x,
        w_ih_l0, w_hh_l0, b_ih_l0, b_hh_l0,
        w_ih_l0r, w_hh_l0r, b_ih_l0r, b_hh_l0r, h1u);
    l1fc_kernel<<<512, 512, 0, stream>>>(h1u,
        w_ih_l1, w_hh_l1, b_ih_l1, b_hh_l1,
        w_ih_l1r, w_hh_l1r, b_ih_l1r, b_hh_l1r,
        (const unsigned*)w2g, fc1_b, fc2_w, fc2_b, (float*)d_out);
}

// Round 4
// 422.712 us; speedup vs baseline: 1.0283x; 1.0187x over previous
//
#include <hip/hip_runtime.h>

#define Bn 65536
#define Tn 100
#define Cn 7

typedef short short8 __attribute__((ext_vector_type(8)));   // 8 bf16 = 4 VGPRs (MFMA A/B frag)
typedef float float4v __attribute__((ext_vector_type(4)));  // MFMA C/D frag

__device__ __forceinline__ float fast_rcp(float x) { return __builtin_amdgcn_rcpf(x); }
__device__ __forceinline__ float sig_f(float x) { return fast_rcp(1.f + __expf(-x)); }
__device__ __forceinline__ float tanh_f(float x) { return 1.f - 2.f * fast_rcp(__expf(2.f * x) + 1.f); }
// round-to-nearest-even fp32 -> bf16 (finite values only)
__device__ __forceinline__ unsigned bf16rne(float x) {
    unsigned u = __float_as_uint(x);
    return (u + 0x7fffu + ((u >> 16) & 1u)) >> 16;
}
__device__ __forceinline__ float bf_lo(unsigned u) { return __uint_as_float(u << 16); }
__device__ __forceinline__ float bf_hi(unsigned u) { return __uint_as_float(u & 0xffff0000u); }

// lane^1 exchange via DPP quad_perm [1,0,3,2] — stays in the VALU pipe (no LDS)
__device__ __forceinline__ float dpp_xor1(float x) {
    return __uint_as_float((unsigned)__builtin_amdgcn_mov_dpp(
        (int)__float_as_uint(x), 0xB1, 0xF, 0xF, true));
}

typedef const __attribute__((address_space(1))) void* gp_t;
typedef __attribute__((address_space(3))) void* sp_t;
__device__ __forceinline__ void async_copy_dw(const void* g, void* l) {
    __builtin_amdgcn_global_load_lds((gp_t)g, (sp_t)l, 4, 0, 0);
}

// ---------------- K0: gather fc1_w into per-(window,dir) bf16 B-panels ----------------
__global__ void w2prep_kernel(const float* __restrict__ fc1_w, unsigned short* __restrict__ w2g) {
    int idx = blockIdx.x * 256 + threadIdx.x;   // 40960 total
    int w  = idx >> 12;
    int d  = (idx >> 11) & 1;
    int n  = (idx >> 5) & 63;
    int kk = idx & 31;
    int tt = kk >> 1, i = kk & 1;
    int t  = d ? (99 - 10 * w - tt) : (10 * w + tt);
    float v = (kk < 20) ? fc1_w[n * 400 + 4 * t + 2 * d + i] : 0.f;
    w2g[idx] = (unsigned short)bf16rne(v);
}

// ---------------- K1: bidirectional LSTM layer 0, channel-split ----------------
// R3: 256-thr blocks over 64 samples (was 512 thr / 128 samples). LDS 35,840 B ->
// 4 blocks/CU x 4 waves = 16 waves/CU truly resident (R2's 512-thr shape only got
// 1 block/CU, nullifying the split). Waves 0/2 stage dirs 0/1; vmcnt(5) unchanged.
__global__ __launch_bounds__(256) void l0_kernel(
    const float* __restrict__ x,
    const float* __restrict__ wih_f, const float* __restrict__ whh_f,
    const float* __restrict__ bih_f, const float* __restrict__ bhh_f,
    const float* __restrict__ wih_r, const float* __restrict__ whh_r,
    const float* __restrict__ bih_r, const float* __restrict__ bhh_r,
    unsigned* __restrict__ h1u)
{
    __shared__ float xs[2][2][2240];   // [parity][dir][64 samples * 35 floats] = 35,840 B

    const int tid  = threadIdx.x;
    const int wv   = tid >> 6;          // 0..3
    const int lane = tid & 63;
    const int rev  = tid >> 7;          // waves 0-1: fwd, 2-3: rev
    const int cid  = tid & 1;           // hidden channel
    const int s    = (tid & 127) >> 1;  // sample in block (0..63)
    const int b    = blockIdx.x * 64 + s;

    const float* wih = rev ? wih_r : wih_f;
    const float* whh = rev ? whh_r : whh_f;
    const float* bih = rev ? bih_r : bih_f;
    const float* bhh = rev ? bhh_r : bhh_f;

    // per-channel gate rows: k = cid + 2*j, j in {i,f,g,o}
    float wi[28], whA[4], whB[4], bias4[4];
#pragma unroll
    for (int j = 0; j < 4; ++j) {
        const int k = cid + 2 * j;
#pragma unroll
        for (int c = 0; c < 7; ++c) wi[j * 7 + c] = wih[k * 7 + c];
        whA[j] = whh[k * 2 + cid];        // coeff of own h
        whB[j] = whh[k * 2 + (cid ^ 1)];  // coeff of partner h
        bias4[j] = bih[k] + bhh[k];
    }

    // staging: wave 0 stages dir 0, wave 2 stages dir 1 (one wave covers 64x35)
    const int stager = ((wv & 1) == 0);
    const int sdir   = wv >> 1;
    const int e  = (lane >= 35) ? 1 : 0;
    const int r0 = lane - 35 * e;
    const float* xsamp = x + (size_t)(blockIdx.x * 64 + e) * 700;

    auto stage = [&](int ch, int p) {
        const int off = sdir ? (665 - 35 * ch) : (35 * ch);
        const float* g = xsamp + off + r0;
        float* l = &xs[p][sdir][lane];
        int r = r0;
#pragma unroll
        for (int i = 0; i < 35; ++i) {
            async_copy_dw(g, l);
            l += 64;
            const int c = (r >= 6) ? 1 : 0;
            g += c ? 1394 : 729;
            r += c ? -6 : 29;
        }
    };

    float hs = 0.f, ho = 0.f, cc = 0.f;

    if (stager) stage(0, 0);
#pragma unroll 1
    for (int chk = 0; chk < 20; ++chk) {
        // stagers: drain 35 chunk loads, leave 5 h1 stores in flight.
        // non-stagers: only 5 stores outstanding -> no-op wait; barrier covers them.
        if (chk == 0) __builtin_amdgcn_s_waitcnt(0x0F70);
        else          __builtin_amdgcn_s_waitcnt(0x0F75);
        __syncthreads();
        if (stager && chk < 19) stage(chk + 1, (chk + 1) & 1);
        __builtin_amdgcn_sched_barrier(0);   // keep stage loads older than compute's stores

        const int t0 = rev ? (95 - 5 * chk) : (5 * chk);
        const float* xbuf = &xs[chk & 1][rev][0];
#pragma unroll
        for (int tt = 0; tt < 5; ++tt) {
            const int rr = rev ? (4 - tt) : tt;
            const int t  = t0 + rr;
            const float* xrow = xbuf + s * 35 + rr * 7;

            float g[4];
#pragma unroll
            for (int j = 0; j < 4; ++j) g[j] = bias4[j];
#pragma unroll
            for (int c = 0; c < 7; ++c) {
                const float xv = xrow[c];
#pragma unroll
                for (int j = 0; j < 4; ++j) g[j] = fmaf(wi[j * 7 + c], xv, g[j]);
            }
#pragma unroll
            for (int j = 0; j < 4; ++j)
                g[j] = fmaf(whA[j], hs, fmaf(whB[j], ho, g[j]));

            const float iv = sig_f(g[0]);
            const float fv = sig_f(g[1]);
            const float qv = tanh_f(g[2]);
            const float ov = sig_f(g[3]);
            cc = fmaf(fv, cc, iv * qv);
            hs = ov * tanh_f(cc);
            ho = dpp_xor1(hs);          // partner channel's h

            if (cid == 0)               // even lanes: pack (h0,h1), 1 store/step/wave
                h1u[((size_t)t * 2 + rev) * Bn + b] = bf16rne(hs) | (bf16rne(ho) << 16);
        }
    }
}

// ---------------- K2: LSTM layer 1 + MFMA-fc1 + fc2, channel-split ----------------
// R3: 256-thr blocks over 64 samples; smem 47,104 B -> 3 blocks/CU (12 waves/CU).
// MFMA: 4 waves x 16 rows of C[64x64].
__global__ __launch_bounds__(256) void l1fc_kernel(
    const unsigned* __restrict__ hin,   // [T][2][B] packed bf16 pairs
    const float* __restrict__ wih_f, const float* __restrict__ whh_f,
    const float* __restrict__ bih_f, const float* __restrict__ bhh_f,
    const float* __restrict__ wih_r, const float* __restrict__ whh_r,
    const float* __restrict__ bih_r, const float* __restrict__ bhh_r,
    const unsigned* __restrict__ w2g,   // [10][2][64][32] bf16 = [10][2][64][16] dw
    const float* __restrict__ fc1_b,
    const float* __restrict__ fc2_w,    // [20][64]
    const float* __restrict__ fc2_b,
    float* __restrict__ out)            // [B][20]
{
    __shared__ unsigned smem[11776];    // 47,104 B
    unsigned* a2  = smem;               // [2][64][20] dw (bf16 pairs; dw 10..15 zero K-pad)
    unsigned* w2b = smem + 2560;        // [2 buf][2 d][64][16] dw
    unsigned* hst = smem + 6656;        // [2 buf][2 d][2 p][10][64] dw

    const int tid  = threadIdx.x;
    const int wv   = tid >> 6;          // 0..3
    const int lane = tid & 63;
    const int d    = tid >> 7;          // waves 0-1: fwd, 2-3: rev
    const int cid  = tid & 1;
    const int s    = (tid & 127) >> 1;  // 0..63
    const int b0   = blockIdx.x * 64;

    const float* wih = d ? wih_r : wih_f;
    const float* whh = d ? whh_r : whh_f;
    const float* bih = d ? bih_r : bih_f;
    const float* bhh = d ? bhh_r : bhh_f;

    float wi[16], whA[4], whB[4], bias4[4];
#pragma unroll
    for (int j = 0; j < 4; ++j) {
        const int k = cid + 2 * j;
#pragma unroll
        for (int m = 0; m < 4; ++m) wi[j * 4 + m] = wih[k * 4 + m];
        whA[j] = whh[k * 2 + cid];
        whB[j] = whh[k * 2 + (cid ^ 1)];
        bias4[j] = bih[k] + bhh[k];
    }

    float4v acc[4];
#pragma unroll
    for (int nt = 0; nt < 4; ++nt) acc[nt] = (float4v){0.f, 0.f, 0.f, 0.f};

    for (int i = tid; i < 2560; i += 256) a2[i] = 0u;   // zero incl. K-pad cols

    // stage h slab for window w into buffer pb: 40 rows R=[dd][p][j] of 64 dwords
    auto stage_h = [&](int w, int pb) {
        unsigned* dst = hst + pb * 2560;
        const int Rb = tid >> 6;           // 0..3
        const int s2 = tid & 63;
#pragma unroll
        for (int i = 0; i < 10; ++i) {
            const int R  = Rb + 4 * i;     // 0..39
            const int dd = (R >= 20) ? 1 : 0;
            const int r2 = R - 20 * dd;
            const int p  = (r2 >= 10) ? 1 : 0;
            const int j  = r2 - 10 * p;
            const int t  = dd ? (99 - (10 * w + j)) : (10 * w + j);
            async_copy_dw(hin + ((size_t)t * 2 + p) * Bn + b0 + s2, dst + R * 64 + s2);
        }
    };
    auto stage_w = [&](int w, int pb) {
        const unsigned* src = w2g + w * 2048;
        unsigned* dst = w2b + pb * 2048;
#pragma unroll
        for (int i = 0; i < 8; ++i)
            async_copy_dw(src + i * 256 + tid, dst + i * 256 + tid);
    };

    stage_h(0, 0); stage_w(0, 0);

    float hs = 0.f, ho = 0.f, cc = 0.f;
    const int q = lane >> 4, l16 = lane & 15;

#pragma unroll 1
    for (int w = 0; w < 10; ++w) {
        __builtin_amdgcn_s_waitcnt(0x0F70);   // this window's slabs arrived
        __syncthreads();                      // (also covers a2-zero at w=0)
        if (w < 9) { stage_h(w + 1, (w + 1) & 1); stage_w(w + 1, (w + 1) & 1); }

        // ---- 10 LSTM steps (LDS-only inputs) ----
        const unsigned* hb = hst + (w & 1) * 2560 + d * 1280;
#pragma unroll 2
        for (int j = 0; j < 10; ++j) {
            const unsigned uF = hb[j * 64 + s];
            const unsigned uR = hb[640 + j * 64 + s];
            const float aF0 = bf_lo(uF), aF1 = bf_hi(uF);
            const float aR0 = bf_lo(uR), aR1 = bf_hi(uR);

            float g[4];
#pragma unroll
            for (int jj = 0; jj < 4; ++jj) {
                g[jj] = bias4[jj];
                g[jj] = fmaf(wi[jj * 4 + 0], aF0, g[jj]);
                g[jj] = fmaf(wi[jj * 4 + 1], aF1, g[jj]);
                g[jj] = fmaf(wi[jj * 4 + 2], aR0, g[jj]);
                g[jj] = fmaf(wi[jj * 4 + 3], aR1, g[jj]);
                g[jj] = fmaf(whA[jj], hs, fmaf(whB[jj], ho, g[jj]));
            }
            const float iv = sig_f(g[0]);
            const float fv = sig_f(g[1]);
            const float qv = tanh_f(g[2]);
            const float ov = sig_f(g[3]);
            cc = fmaf(fv, cc, iv * qv);
            hs = ov * tanh_f(cc);
            ho = dpp_xor1(hs);

            if (cid == 0)
                a2[d * 1280 + s * 20 + j] =
                    bf16rne(fmaxf(hs, 0.f)) | (bf16rne(fmaxf(ho, 0.f)) << 16);
        }
        __syncthreads();   // a2 complete

        // ---- MFMA: C[64x64] += A2[dd]·W2[dd]^T, K=32; 4 waves x 16 rows ----
        {
            const unsigned* wb = w2b + (w & 1) * 2048;
#pragma unroll
            for (int dd = 0; dd < 2; ++dd) {
                short8 av = *(const short8*)&a2[dd * 1280 + (wv * 16 + l16) * 20 + q * 4];
                short8 bv[4];
#pragma unroll
                for (int nt = 0; nt < 4; ++nt)
                    bv[nt] = *(const short8*)&wb[dd * 1024 + (nt * 16 + l16) * 16 + q * 4];
#pragma unroll
                for (int nt = 0; nt < 4; ++nt)
                    acc[nt] = __builtin_amdgcn_mfma_f32_16x16x32_bf16(
                        av, bv[nt], acc[nt], 0, 0, 0);
            }
        }
        // next window's top barrier separates these MFMA reads from the next a2 writes
    }
    __syncthreads();

    // ---- epilogue: C -> LDS, +bias, relu, fc2, out ----
    {
        float* eb = (float*)smem;          // [64][65]
#pragma unroll
        for (int nt = 0; nt < 4; ++nt)
#pragma unroll
            for (int r = 0; r < 4; ++r) {
                const int sl = wv * 16 + q * 4 + r;
                const int cl = nt * 16 + l16;
                eb[sl * 65 + cl] = acc[nt][r];
            }
    }
    __syncthreads();

    const float* eb = (const float*)smem;
    const int sm2 = tid & 63;
    const int og  = (tid >> 6) * 5;        // 4 groups x 5 outputs
    float z[64];
#pragma unroll
    for (int k = 0; k < 64; ++k) z[k] = fmaxf(eb[sm2 * 65 + k] + fc1_b[k], 0.f);
    float y[5];
#pragma unroll
    for (int o = 0; o < 5; ++o) {
        float r2 = fc2_b[og + o];
#pragma unroll
        for (int k = 0; k < 64; ++k) r2 = fmaf(fc2_w[(og + o) * 64 + k], z[k], r2);
        y[o] = r2;
    }
    __syncthreads();
    float* ebw = (float*)smem;
#pragma unroll
    for (int o = 0; o < 5; ++o) ebw[sm2 * 20 + og + o] = y[o];
    __syncthreads();
    for (int f = tid; f < 1280; f += 256)
        out[(size_t)blockIdx.x * 1280 + f] = ebw[f];
}

extern "C" void kernel_launch(void* const* d_in, const int* in_sizes, int n_in,
                              void* d_out, int out_size, void* d_ws, size_t ws_size,
                              hipStream_t stream) {
    const float* x = (const float*)d_in[0];
    const float* w_ih_l0  = (const float*)d_in[1];
    const float* w_hh_l0  = (const float*)d_in[2];
    const float* b_ih_l0  = (const float*)d_in[3];
    const float* b_hh_l0  = (const float*)d_in[4];
    const float* w_ih_l0r = (const float*)d_in[5];
    const float* w_hh_l0r = (const float*)d_in[6];
    const float* b_ih_l0r = (const float*)d_in[7];
    const float* b_hh_l0r = (const float*)d_in[8];
    const float* w_ih_l1  = (const float*)d_in[9];
    const float* w_hh_l1  = (const float*)d_in[10];
    const float* b_ih_l1  = (const float*)d_in[11];
    const float* b_hh_l1  = (const float*)d_in[12];
    const float* w_ih_l1r = (const float*)d_in[13];
    const float* w_hh_l1r = (const float*)d_in[14];
    const float* b_ih_l1r = (const float*)d_in[15];
    const float* b_hh_l1r = (const float*)d_in[16];
    const float* fc1_w = (const float*)d_in[17];
    const float* fc1_b = (const float*)d_in[18];
    const float* fc2_w = (const float*)d_in[19];
    const float* fc2_b = (const float*)d_in[20];

    unsigned* h1u = (unsigned*)d_ws;                                // [100][2][65536] u32 = 52,428,800 B
    unsigned short* w2g = (unsigned short*)((char*)d_ws + (size_t)Tn * 2 * Bn * 4);  // 81,920 B

    w2prep_kernel<<<160, 256, 0, stream>>>(fc1_w, w2g);
    l0_kernel<<<1024, 256, 0, stream>>>(x,
        w_ih_l0, w_hh_l0, b_ih_l0, b_hh_l0,
        w_ih_l0r, w_hh_l0r, b_ih_l0r, b_hh_l0r, h1u);
    l1fc_kernel<<<1024, 256, 0, stream>>>(h1u,
        w_ih_l1, w_hh_l1, b_ih_l1, b_hh_l1,
        w_ih_l1r, w_hh_l1r, b_ih_l1r, b_hh_l1r,
        (const unsigned*)w2g, fc1_b, fc2_w, fc2_b, (float*)d_out);
}

// Round 5
// 414.913 us; speedup vs baseline: 1.0477x; 1.0188x over previous
//
#include <hip/hip_runtime.h>

#define Bn 65536
#define Tn 100
#define Cn 7

typedef short short8 __attribute__((ext_vector_type(8)));   // 8 bf16 = 4 VGPRs (MFMA A/B frag)
typedef float float4v __attribute__((ext_vector_type(4)));  // MFMA C/D frag

__device__ __forceinline__ float fast_rcp(float x) { return __builtin_amdgcn_rcpf(x); }
__device__ __forceinline__ float sig_f(float x) { return fast_rcp(1.f + __expf(-x)); }
__device__ __forceinline__ float tanh_f(float x) { return 1.f - 2.f * fast_rcp(__expf(2.f * x) + 1.f); }
// round-to-nearest-even fp32 -> bf16 (finite values only)
__device__ __forceinline__ unsigned bf16rne(float x) {
    unsigned u = __float_as_uint(x);
    return (u + 0x7fffu + ((u >> 16) & 1u)) >> 16;
}
__device__ __forceinline__ float bf_lo(unsigned u) { return __uint_as_float(u << 16); }
__device__ __forceinline__ float bf_hi(unsigned u) { return __uint_as_float(u & 0xffff0000u); }

// lane^1 exchange via DPP quad_perm [1,0,3,2] — stays in the VALU pipe (no LDS)
__device__ __forceinline__ float dpp_xor1(float x) {
    return __uint_as_float((unsigned)__builtin_amdgcn_mov_dpp(
        (int)__float_as_uint(x), 0xB1, 0xF, 0xF, true));
}

typedef const __attribute__((address_space(1))) void* gp_t;
typedef __attribute__((address_space(3))) void* sp_t;
__device__ __forceinline__ void async_copy_dw(const void* g, void* l) {
    __builtin_amdgcn_global_load_lds((gp_t)g, (sp_t)l, 4, 0, 0);
}

// ---------------- K0: gather fc1_w into per-(window,dir) bf16 B-panels ----------------
__global__ void w2prep_kernel(const float* __restrict__ fc1_w, unsigned short* __restrict__ w2g) {
    int idx = blockIdx.x * 256 + threadIdx.x;   // 40960 total
    int w  = idx >> 12;
    int d  = (idx >> 11) & 1;
    int n  = (idx >> 5) & 63;
    int kk = idx & 31;
    int tt = kk >> 1, i = kk & 1;
    int t  = d ? (99 - 10 * w - tt) : (10 * w + tt);
    float v = (kk < 20) ? fc1_w[n * 400 + 4 * t + 2 * d + i] : 0.f;
    w2g[idx] = (unsigned short)bf16rne(v);
}

// ---------------- K1: bidirectional LSTM layer 0, channel-split, BARRIER-FREE ----------------
// R4 post-mortem: dur invariant across ILP/TLP changes; VALUBusy 54% at 4 waves/SIMD
// resident => 46% all-waves-idle at the lockstep chunk barrier. R5: each wave stages
// its OWN 32-sample x-panel (18 async loads/chunk, wave-private LDS) -> __syncthreads
// deleted; waves free-run on private vmcnt(5) discipline and desynchronize.
__global__ __launch_bounds__(256) void l0_kernel(
    const float* __restrict__ x,
    const float* __restrict__ wih_f, const float* __restrict__ whh_f,
    const float* __restrict__ bih_f, const float* __restrict__ bhh_f,
    const float* __restrict__ wih_r, const float* __restrict__ whh_r,
    const float* __restrict__ bih_r, const float* __restrict__ bhh_r,
    unsigned* __restrict__ h1u)
{
    __shared__ float xs[4][2][1120];   // [wave][parity][32 samples * 35 floats] = 35,840 B

    const int tid  = threadIdx.x;
    const int wv   = tid >> 6;          // 0..3
    const int lane = tid & 63;
    const int rev  = wv >> 1;           // waves 0-1: fwd, 2-3: rev
    const int sgrp = wv & 1;            // sample group within block
    const int cid  = lane & 1;          // hidden channel
    const int s    = lane >> 1;         // sample within wave (0..31)
    const int b    = blockIdx.x * 64 + sgrp * 32 + s;

    const float* wih = rev ? wih_r : wih_f;
    const float* whh = rev ? whh_r : whh_f;
    const float* bih = rev ? bih_r : bih_f;
    const float* bhh = rev ? bhh_r : bhh_f;

    // per-channel gate rows: k = cid + 2*j, j in {i,f,g,o}
    float wi[28], whA[4], whB[4], bias4[4];
#pragma unroll
    for (int j = 0; j < 4; ++j) {
        const int k = cid + 2 * j;
#pragma unroll
        for (int c = 0; c < 7; ++c) wi[j * 7 + c] = wih[k * 7 + c];
        whA[j] = whh[k * 2 + cid];        // coeff of own h
        whB[j] = whh[k * 2 + (cid ^ 1)];  // coeff of partner h
        bias4[j] = bih[k] + bhh[k];
    }

    // per-wave private staging: 32 samples x 35 floats = 1120 elems = 17.5 wave-loads.
    // Element idx = i*64 + lane -> (sample = idx/35, r = idx%35); incremental walk:
    // r<6 -> next sample (+729 floats), else skip a sample boundary (+1394, r-6).
    const int e  = (lane >= 35) ? 1 : 0;
    const int r0 = lane - 35 * e;
    const float* xsamp = x + (size_t)(blockIdx.x * 64 + sgrp * 32 + e) * 700;

    auto stage = [&](int ch, int p) {
        const int off = rev ? (665 - 35 * ch) : (35 * ch);
        const float* g = xsamp + off + r0;
        float* l = &xs[wv][p][lane];
        int r = r0;
#pragma unroll
        for (int i = 0; i < 17; ++i) {
            async_copy_dw(g, l);
            l += 64;
            const int c = (r >= 6) ? 1 : 0;
            g += c ? 1394 : 729;
            r += c ? -6 : 29;
        }
        if (lane < 32) async_copy_dw(g, l);   // tail: elems 1088..1119 (sample 31)
    };

    float hs = 0.f, ho = 0.f, cc = 0.f;

    stage(0, 0);
#pragma unroll 1
    for (int chk = 0; chk < 20; ++chk) {
        // drain this wave's 18 chunk loads; leave the 5 newest (h1 stores) in flight
        if (chk == 0) __builtin_amdgcn_s_waitcnt(0x0F70);
        else          __builtin_amdgcn_s_waitcnt(0x0F75);
        __builtin_amdgcn_sched_barrier(0);   // fence: no ds_read hoists above the wait
        if (chk < 19) stage(chk + 1, (chk + 1) & 1);
        __builtin_amdgcn_sched_barrier(0);   // keep stage loads older than compute's stores

        const int t0 = rev ? (95 - 5 * chk) : (5 * chk);
        const float* xbuf = &xs[wv][chk & 1][0];
#pragma unroll
        for (int tt = 0; tt < 5; ++tt) {
            const int rr = rev ? (4 - tt) : tt;
            const int t  = t0 + rr;
            const float* xrow = xbuf + s * 35 + rr * 7;

            float g[4];
#pragma unroll
            for (int j = 0; j < 4; ++j) g[j] = bias4[j];
#pragma unroll
            for (int c = 0; c < 7; ++c) {
                const float xv = xrow[c];
#pragma unroll
                for (int j = 0; j < 4; ++j) g[j] = fmaf(wi[j * 7 + c], xv, g[j]);
            }
#pragma unroll
            for (int j = 0; j < 4; ++j)
                g[j] = fmaf(whA[j], hs, fmaf(whB[j], ho, g[j]));

            const float iv = sig_f(g[0]);
            const float fv = sig_f(g[1]);
            const float qv = tanh_f(g[2]);
            const float ov = sig_f(g[3]);
            cc = fmaf(fv, cc, iv * qv);
            hs = ov * tanh_f(cc);
            ho = dpp_xor1(hs);          // partner channel's h

            if (cid == 0)               // even lanes: pack (h0,h1), 1 store/step/wave
                h1u[((size_t)t * 2 + rev) * Bn + b] = bf16rne(hs) | (bf16rne(ho) << 16);
        }
    }
}

// ---------------- K2: LSTM layer 1 + MFMA-fc1 + fc2, channel-split ----------------
// (unchanged from R3/R4: 256-thr blocks over 64 samples; smem 47,104 B; MFMA 4 waves x 16 rows)
__global__ __launch_bounds__(256) void l1fc_kernel(
    const unsigned* __restrict__ hin,   // [T][2][B] packed bf16 pairs
    const float* __restrict__ wih_f, const float* __restrict__ whh_f,
    const float* __restrict__ bih_f, const float* __restrict__ bhh_f,
    const float* __restrict__ wih_r, const float* __restrict__ whh_r,
    const float* __restrict__ bih_r, const float* __restrict__ bhh_r,
    const unsigned* __restrict__ w2g,   // [10][2][64][32] bf16 = [10][2][64][16] dw
    const float* __restrict__ fc1_b,
    const float* __restrict__ fc2_w,    // [20][64]
    const float* __restrict__ fc2_b,
    float* __restrict__ out)            // [B][20]
{
    __shared__ unsigned smem[11776];    // 47,104 B
    unsigned* a2  = smem;               // [2][64][20] dw (bf16 pairs; dw 10..15 zero K-pad)
    unsigned* w2b = smem + 2560;        // [2 buf][2 d][64][16] dw
    unsigned* hst = smem + 6656;        // [2 buf][2 d][2 p][10][64] dw

    const int tid  = threadIdx.x;
    const int wv   = tid >> 6;          // 0..3
    const int lane = tid & 63;
    const int d    = tid >> 7;          // waves 0-1: fwd, 2-3: rev
    const int cid  = tid & 1;
    const int s    = (tid & 127) >> 1;  // 0..63
    const int b0   = blockIdx.x * 64;

    const float* wih = d ? wih_r : wih_f;
    const float* whh = d ? whh_r : whh_f;
    const float* bih = d ? bih_r : bih_f;
    const float* bhh = d ? bhh_r : bhh_f;

    float wi[16], whA[4], whB[4], bias4[4];
#pragma unroll
    for (int j = 0; j < 4; ++j) {
        const int k = cid + 2 * j;
#pragma unroll
        for (int m = 0; m < 4; ++m) wi[j * 4 + m] = wih[k * 4 + m];
        whA[j] = whh[k * 2 + cid];
        whB[j] = whh[k * 2 + (cid ^ 1)];
        bias4[j] = bih[k] + bhh[k];
    }

    float4v acc[4];
#pragma unroll
    for (int nt = 0; nt < 4; ++nt) acc[nt] = (float4v){0.f, 0.f, 0.f, 0.f};

    for (int i = tid; i < 2560; i += 256) a2[i] = 0u;   // zero incl. K-pad cols

    // stage h slab for window w into buffer pb: 40 rows R=[dd][p][j] of 64 dwords
    auto stage_h = [&](int w, int pb) {
        unsigned* dst = hst + pb * 2560;
        const int Rb = tid >> 6;           // 0..3
        const int s2 = tid & 63;
#pragma unroll
        for (int i = 0; i < 10; ++i) {
            const int R  = Rb + 4 * i;     // 0..39
            const int dd = (R >= 20) ? 1 : 0;
            const int r2 = R - 20 * dd;
            const int p  = (r2 >= 10) ? 1 : 0;
            const int j  = r2 - 10 * p;
            const int t  = dd ? (99 - (10 * w + j)) : (10 * w + j);
            async_copy_dw(hin + ((size_t)t * 2 + p) * Bn + b0 + s2, dst + R * 64 + s2);
        }
    };
    auto stage_w = [&](int w, int pb) {
        const unsigned* src = w2g + w * 2048;
        unsigned* dst = w2b + pb * 2048;
#pragma unroll
        for (int i = 0; i < 8; ++i)
            async_copy_dw(src + i * 256 + tid, dst + i * 256 + tid);
    };

    stage_h(0, 0); stage_w(0, 0);

    float hs = 0.f, ho = 0.f, cc = 0.f;
    const int q = lane >> 4, l16 = lane & 15;

#pragma unroll 1
    for (int w = 0; w < 10; ++w) {
        __builtin_amdgcn_s_waitcnt(0x0F70);   // this window's slabs arrived
        __syncthreads();                      // (also covers a2-zero at w=0)
        if (w < 9) { stage_h(w + 1, (w + 1) & 1); stage_w(w + 1, (w + 1) & 1); }

        // ---- 10 LSTM steps (LDS-only inputs) ----
        const unsigned* hb = hst + (w & 1) * 2560 + d * 1280;
#pragma unroll 2
        for (int j = 0; j < 10; ++j) {
            const unsigned uF = hb[j * 64 + s];
            const unsigned uR = hb[640 + j * 64 + s];
            const float aF0 = bf_lo(uF), aF1 = bf_hi(uF);
            const float aR0 = bf_lo(uR), aR1 = bf_hi(uR);

            float g[4];
#pragma unroll
            for (int jj = 0; jj < 4; ++jj) {
                g[jj] = bias4[jj];
                g[jj] = fmaf(wi[jj * 4 + 0], aF0, g[jj]);
                g[jj] = fmaf(wi[jj * 4 + 1], aF1, g[jj]);
                g[jj] = fmaf(wi[jj * 4 + 2], aR0, g[jj]);
                g[jj] = fmaf(wi[jj * 4 + 3], aR1, g[jj]);
                g[jj] = fmaf(whA[jj], hs, fmaf(whB[jj], ho, g[jj]));
            }
            const float iv = sig_f(g[0]);
            const float fv = sig_f(g[1]);
            const float qv = tanh_f(g[2]);
            const float ov = sig_f(g[3]);
            cc = fmaf(fv, cc, iv * qv);
            hs = ov * tanh_f(cc);
            ho = dpp_xor1(hs);

            if (cid == 0)
                a2[d * 1280 + s * 20 + j] =
                    bf16rne(fmaxf(hs, 0.f)) | (bf16rne(fmaxf(ho, 0.f)) << 16);
        }
        __syncthreads();   // a2 complete

        // ---- MFMA: C[64x64] += A2[dd]·W2[dd]^T, K=32; 4 waves x 16 rows ----
        {
            const unsigned* wb = w2b + (w & 1) * 2048;
#pragma unroll
            for (int dd = 0; dd < 2; ++dd) {
                short8 av = *(const short8*)&a2[dd * 1280 + (wv * 16 + l16) * 20 + q * 4];
                short8 bv[4];
#pragma unroll
                for (int nt = 0; nt < 4; ++nt)
                    bv[nt] = *(const short8*)&wb[dd * 1024 + (nt * 16 + l16) * 16 + q * 4];
#pragma unroll
                for (int nt = 0; nt < 4; ++nt)
                    acc[nt] = __builtin_amdgcn_mfma_f32_16x16x32_bf16(
                        av, bv[nt], acc[nt], 0, 0, 0);
            }
        }
        // next window's top barrier separates these MFMA reads from the next a2 writes
    }
    __syncthreads();

    // ---- epilogue: C -> LDS, +bias, relu, fc2, out ----
    {
        float* eb = (float*)smem;          // [64][65]
#pragma unroll
        for (int nt = 0; nt < 4; ++nt)
#pragma unroll
            for (int r = 0; r < 4; ++r) {
                const int sl = wv * 16 + q * 4 + r;
                const int cl = nt * 16 + l16;
                eb[sl * 65 + cl] = acc[nt][r];
            }
    }
    __syncthreads();

    const float* eb = (const float*)smem;
    const int sm2 = tid & 63;
    const int og  = (tid >> 6) * 5;        // 4 groups x 5 outputs
    float z[64];
#pragma unroll
    for (int k = 0; k < 64; ++k) z[k] = fmaxf(eb[sm2 * 65 + k] + fc1_b[k], 0.f);
    float y[5];
#pragma unroll
    for (int o = 0; o < 5; ++o) {
        float r2 = fc2_b[og + o];
#pragma unroll
        for (int k = 0; k < 64; ++k) r2 = fmaf(fc2_w[(og + o) * 64 + k], z[k], r2);
        y[o] = r2;
    }
    __syncthreads();
    float* ebw = (float*)smem;
#pragma unroll
    for (int o = 0; o < 5; ++o) ebw[sm2 * 20 + og + o] = y[o];
    __syncthreads();
    for (int f = tid; f < 1280; f += 256)
        out[(size_t)blockIdx.x * 1280 + f] = ebw[f];
}

extern "C" void kernel_launch(void* const* d_in, const int* in_sizes, int n_in,
                              void* d_out, int out_size, void* d_ws, size_t ws_size,
                              hipStream_t stream) {
    const float* x = (const float*)d_in[0];
    const float* w_ih_l0  = (const float*)d_in[1];
    const float* w_hh_l0  = (const float*)d_in[2];
    const float* b_ih_l0  = (const float*)d_in[3];
    const float* b_hh_l0  = (const float*)d_in[4];
    const float* w_ih_l0r = (const float*)d_in[5];
    const float* w_hh_l0r = (const float*)d_in[6];
    const float* b_ih_l0r = (const float*)d_in[7];
    const float* b_hh_l0r = (const float*)d_in[8];
    const float* w_ih_l1  = (const float*)d_in[9];
    const float* w_hh_l1  = (const float*)d_in[10];
    const float* b_ih_l1  = (const float*)d_in[11];
    const float* b_hh_l1  = (const float*)d_in[12];
    const float* w_ih_l1r = (const float*)d_in[13];
    const float* w_hh_l1r = (const float*)d_in[14];
    const float* b_ih_l1r = (const float*)d_in[15];
    const float* b_hh_l1r = (const float*)d_in[16];
    const float* fc1_w = (const float*)d_in[17];
    const float* fc1_b = (const float*)d_in[18];
    const float* fc2_w = (const float*)d_in[19];
    const float* fc2_b = (const float*)d_in[20];

    unsigned* h1u = (unsigned*)d_ws;                                // [100][2][65536] u32 = 52,428,800 B
    unsigned short* w2g = (unsigned short*)((char*)d_ws + (size_t)Tn * 2 * Bn * 4);  // 81,920 B

    w2prep_kernel<<<160, 256, 0, stream>>>(fc1_w, w2g);
    l0_kernel<<<1024, 256, 0, stream>>>(x,
        w_ih_l0, w_hh_l0, b_ih_l0, b_hh_l0,
        w_ih_l0r, w_hh_l0r, b_ih_l0r, b_hh_l0r, h1u);
    l1fc_kernel<<<1024, 256, 0, stream>>>(h1u,
        w_ih_l1, w_hh_l1, b_ih_l1, b_hh_l1,
        w_ih_l1r, w_hh_l1r, b_ih_l1r, b_hh_l1r,
        (const unsigned*)w2g, fc1_b, fc2_w, fc2_b, (float*)d_out);
}